// Round 1
// baseline (4192.628 us; speedup 1.0000x reference)
//
#include <hip/hip_runtime.h>

#define DD 8
#define HH 256

// ---------------------------------------------------------------------------
// unsafeAtomicAdd lowers to global_atomic_add_f32 on gfx950 (HW f32 atomic).
// Plain atomicAdd(float*) without -munsafe-fp-atomics becomes a CAS loop.
// ---------------------------------------------------------------------------
static __device__ __forceinline__ void faa(float* p, float v) {
    unsafeAtomicAdd(p, v);
}

// --- degree counting --------------------------------------------------------
__global__ void k_deg(const int* __restrict__ src, const int* __restrict__ dst,
                      float* __restrict__ deg_out, float* __restrict__ deg_in, int E) {
    int e = blockIdx.x * blockDim.x + threadIdx.x;
    if (e >= E) return;
    faa(&deg_out[src[e]], 1.0f);
    faa(&deg_in[dst[e]], 1.0f);
}

// --- per-node prep: norms, mass diagonal, scaled q, and dHdP output --------
__global__ void k_prep(const float* __restrict__ q, const float* __restrict__ p,
                       const float* __restrict__ M,
                       const float* __restrict__ deg_out, const float* __restrict__ deg_in,
                       float* __restrict__ a, float* __restrict__ b,
                       float* __restrict__ md, float* __restrict__ qn,
                       float* __restrict__ out, int N) {
    int v = blockIdx.x * blockDim.x + threadIdx.x;
    if (v >= N) return;
    float dout = deg_out[v], din = deg_in[v];
    float av = 1.0f / sqrtf(dout > 0.f ? dout : 1.f);   // norm_src
    float bv = 1.0f / sqrtf(din > 0.f ? din : 1.f);     // norm_dst
    a[v] = av; b[v] = bv;
#pragma unroll
    for (int d = 0; d < DD; d++) {
        float m = M[(size_t)v * DD * DD + d * (DD + 1)];  // diagonal entry
        md[(size_t)v * DD + d] = m;
        qn[(size_t)v * DD + d] = av * q[(size_t)v * DD + d];
        // dHdP = p / mdiag  (solve with diagonal M^T)
        out[(size_t)v * 2 * DD + DD + d] = p[(size_t)v * DD + d] / m;
    }
}

// --- generic 8-float edge scatter-add: outp[to[e]] += x[from[e]] ------------
__global__ void k_scatter8(const int* __restrict__ from, const int* __restrict__ to,
                           const float* __restrict__ x, float* __restrict__ outp, int E) {
    int e = blockIdx.x * blockDim.x + threadIdx.x;
    if (e >= E) return;
    int f = from[e], t = to[e];
    const float4* xf = (const float4*)(x + (size_t)f * DD);
    float4 v0 = xf[0], v1 = xf[1];
    float* o = outp + (size_t)t * DD;
    faa(o + 0, v0.x); faa(o + 1, v0.y); faa(o + 2, v0.z); faa(o + 3, v0.w);
    faa(o + 4, v1.x); faa(o + 5, v1.y); faa(o + 6, v1.z); faa(o + 7, v1.w);
}

// --- forward dense: z1 = b*agg1 ; u = z1@W1+b1 ; y = relu(u)@W2 ; ya = a*y --
__launch_bounds__(256)
__global__ void k_fwd_dense(const float* __restrict__ agg1, const float* __restrict__ a,
                            const float* __restrict__ b,
                            const float* __restrict__ W1, const float* __restrict__ b1,
                            const float* __restrict__ W2,
                            float* __restrict__ z1out, float* __restrict__ ya, int N) {
    __shared__ float sW1[DD * HH];   // [d][j]
    __shared__ float sW2[HH * DD];   // [j][d]
    __shared__ float sb1[HH];
    for (int i = threadIdx.x; i < DD * HH; i += blockDim.x) { sW1[i] = W1[i]; sW2[i] = W2[i]; }
    for (int i = threadIdx.x; i < HH; i += blockDim.x) sb1[i] = b1[i];
    __syncthreads();
    int v = blockIdx.x * blockDim.x + threadIdx.x;
    if (v >= N) return;
    float z[DD], y[DD];
    float bv = b[v];
#pragma unroll
    for (int d = 0; d < DD; d++) { z[d] = bv * agg1[(size_t)v * DD + d]; y[d] = 0.f; }
#pragma unroll
    for (int d = 0; d < DD; d++) z1out[(size_t)v * DD + d] = z[d];
    for (int j = 0; j < HH; j++) {
        float u = sb1[j];
#pragma unroll
        for (int d = 0; d < DD; d++) u = fmaf(z[d], sW1[d * HH + j], u);
        float hh = fmaxf(u, 0.f);
#pragma unroll
        for (int d = 0; d < DD; d++) y[d] = fmaf(hh, sW2[j * DD + d], y[d]);
    }
    float av = a[v];
#pragma unroll
    for (int d = 0; d < DD; d++) ya[(size_t)v * DD + d] = av * y[d];
}

// --- h = b*agg2 + b2 + q ----------------------------------------------------
__global__ void k_h(const float* __restrict__ agg2, const float* __restrict__ b,
                    const float* __restrict__ q, const float* __restrict__ b2,
                    float* __restrict__ h, int N) {
    int v = blockIdx.x * blockDim.x + threadIdx.x;
    if (v >= N) return;
    float bv = b[v];
#pragma unroll
    for (int d = 0; d < DD; d++)
        h[(size_t)v * DD + d] = fmaf(bv, agg2[(size_t)v * DD + d],
                                     b2[d] + q[(size_t)v * DD + d]);
}

// --- edge gradient: c = -0.5*g*S/euclid^3 ; gh[s]+=c*diff ; gh[d]-=c*diff ---
__global__ void k_edgegrad(const int* __restrict__ src, const int* __restrict__ dst,
                           const float* __restrict__ h, const float* __restrict__ md,
                           const float* __restrict__ grav, float* __restrict__ gh, int E) {
    int e = blockIdx.x * blockDim.x + threadIdx.x;
    if (e >= E) return;
    int s = src[e], d = dst[e];
    const float4* hs = (const float4*)(h  + (size_t)s * DD);
    const float4* hd = (const float4*)(h  + (size_t)d * DD);
    const float4* ms = (const float4*)(md + (size_t)s * DD);
    const float4* mD = (const float4*)(md + (size_t)d * DD);
    float4 a0 = hs[0], a1 = hs[1], b0 = hd[0], b1 = hd[1];
    float4 m0 = ms[0], m1 = ms[1], n0 = mD[0], n1 = mD[1];
    float diff[DD];
    diff[0] = a0.x - b0.x; diff[1] = a0.y - b0.y; diff[2] = a0.z - b0.z; diff[3] = a0.w - b0.w;
    diff[4] = a1.x - b1.x; diff[5] = a1.y - b1.y; diff[6] = a1.z - b1.z; diff[7] = a1.w - b1.w;
    float e2 = 0.f;
#pragma unroll
    for (int i = 0; i < DD; i++) e2 = fmaf(diff[i], diff[i], e2);
    float S = m0.x * n0.x + m0.y * n0.y + m0.z * n0.z + m0.w * n0.w
            + m1.x * n1.x + m1.y * n1.y + m1.z * n1.z + m1.w * n1.w;
    float eu = sqrtf(e2);
    float c = -0.5f * grav[0] * S / (e2 * eu);
    float* gs = gh + (size_t)s * DD;
    float* gd = gh + (size_t)d * DD;
#pragma unroll
    for (int i = 0; i < DD; i++) { faa(gs + i, c * diff[i]); }
#pragma unroll
    for (int i = 0; i < DD; i++) { faa(gd + i, -c * diff[i]); }
}

// --- bgh = b * gh -----------------------------------------------------------
__global__ void k_bgh(const float* __restrict__ gh, const float* __restrict__ b,
                      float* __restrict__ bgh, int N) {
    int v = blockIdx.x * blockDim.x + threadIdx.x;
    if (v >= N) return;
    float bv = b[v];
#pragma unroll
    for (int d = 0; d < DD; d++) bgh[(size_t)v * DD + d] = bv * gh[(size_t)v * DD + d];
}

// --- backward dense: recompute u; gz1b = b * (((a*(gq2@W2^T))⊙(u>0))@W1^T) --
__launch_bounds__(256)
__global__ void k_bwd_dense(const float* __restrict__ gq2, const float* __restrict__ z1,
                            const float* __restrict__ a, const float* __restrict__ b,
                            const float* __restrict__ W1, const float* __restrict__ b1,
                            const float* __restrict__ W2,
                            float* __restrict__ gz1b, int N) {
    __shared__ float sW1[DD * HH];
    __shared__ float sW2[HH * DD];
    __shared__ float sb1[HH];
    for (int i = threadIdx.x; i < DD * HH; i += blockDim.x) { sW1[i] = W1[i]; sW2[i] = W2[i]; }
    for (int i = threadIdx.x; i < HH; i += blockDim.x) sb1[i] = b1[i];
    __syncthreads();
    int v = blockIdx.x * blockDim.x + threadIdx.x;
    if (v >= N) return;
    float z[DD], gq[DD], gz[DD];
#pragma unroll
    for (int d = 0; d < DD; d++) {
        z[d]  = z1[(size_t)v * DD + d];
        gq[d] = gq2[(size_t)v * DD + d];
        gz[d] = 0.f;
    }
    float av = a[v];
    for (int j = 0; j < HH; j++) {
        float u = sb1[j];
#pragma unroll
        for (int d = 0; d < DD; d++) u = fmaf(z[d], sW1[d * HH + j], u);
        float g = 0.f;
#pragma unroll
        for (int d = 0; d < DD; d++) g = fmaf(gq[d], sW2[j * DD + d], g);
        g = (u > 0.f) ? av * g : 0.f;
#pragma unroll
        for (int d = 0; d < DD; d++) gz[d] = fmaf(g, sW1[d * HH + j], gz[d]);
    }
    float bv = b[v];
#pragma unroll
    for (int d = 0; d < DD; d++) gz1b[(size_t)v * DD + d] = bv * gz[d];
}

// --- final: dHdQ = gh + a * r1 ---------------------------------------------
__global__ void k_out(const float* __restrict__ gh, const float* __restrict__ r1,
                      const float* __restrict__ a, float* __restrict__ out, int N) {
    int v = blockIdx.x * blockDim.x + threadIdx.x;
    if (v >= N) return;
    float av = a[v];
#pragma unroll
    for (int d = 0; d < DD; d++)
        out[(size_t)v * 2 * DD + d] = fmaf(av, r1[(size_t)v * DD + d],
                                           gh[(size_t)v * DD + d]);
}

extern "C" void kernel_launch(void* const* d_in, const int* in_sizes, int n_in,
                              void* d_out, int out_size, void* d_ws, size_t ws_size,
                              hipStream_t stream) {
    const float* q    = (const float*)d_in[0];
    const float* p    = (const float*)d_in[1];
    const float* M    = (const float*)d_in[2];
    const int*   src  = (const int*)d_in[3];
    const int*   dst  = (const int*)d_in[4];
    const float* W1   = (const float*)d_in[5];
    const float* b1   = (const float*)d_in[6];
    const float* W2   = (const float*)d_in[7];
    const float* b2   = (const float*)d_in[8];
    const float* grav = (const float*)d_in[9];
    float* out = (float*)d_out;

    int N = in_sizes[0] / DD;
    int E = in_sizes[3];

    float* ws = (float*)d_ws;
    size_t n = (size_t)N;
    // zeroed region (first 42N floats):
    float* deg_out = ws;             // N
    float* deg_in  = ws + n;         // N
    float* agg1    = ws + 2 * n;     // 8N
    float* agg2    = ws + 10 * n;    // 8N
    float* gh      = ws + 18 * n;    // 8N
    float* gq2     = ws + 26 * n;    // 8N
    float* r1      = ws + 34 * n;    // 8N
    // write-before-read region:
    float* a_      = ws + 42 * n;    // N
    float* b_      = ws + 43 * n;    // N
    float* md      = ws + 44 * n;    // 8N
    float* qn      = ws + 52 * n;    // 8N
    float* z1      = ws + 60 * n;    // 8N
    float* ya      = ws + 68 * n;    // 8N
    float* hbuf    = ws + 76 * n;    // 8N
    float* bgh     = ws + 84 * n;    // 8N
    float* gz1b    = ws + 92 * n;    // 8N
    // total: 100N floats = 40 MB

    hipMemsetAsync(d_ws, 0, 42 * n * sizeof(float), stream);

    const int tb = 256;
    int gbE = (E + tb - 1) / tb;
    int gbN = (N + tb - 1) / tb;

    k_deg      <<<gbE, tb, 0, stream>>>(src, dst, deg_out, deg_in, E);
    k_prep     <<<gbN, tb, 0, stream>>>(q, p, M, deg_out, deg_in, a_, b_, md, qn, out, N);
    // z1 = b ⊙ Agg(a ⊙ q)
    k_scatter8 <<<gbE, tb, 0, stream>>>(src, dst, qn, agg1, E);
    k_fwd_dense<<<gbN, tb, 0, stream>>>(agg1, a_, b_, W1, b1, W2, z1, ya, N);
    // h = b ⊙ Agg(a ⊙ (relu(u)@W2)) + b2 + q
    k_scatter8 <<<gbE, tb, 0, stream>>>(src, dst, ya, agg2, E);
    k_h        <<<gbN, tb, 0, stream>>>(agg2, b_, q, b2, hbuf, N);
    // edge-pair gravity gradient wrt h
    k_edgegrad <<<gbE, tb, 0, stream>>>(src, dst, hbuf, md, grav, gh, E);
    // gq2 = Agg^T(b ⊙ gh)
    k_bgh      <<<gbN, tb, 0, stream>>>(gh, b_, bgh, N);
    k_scatter8 <<<gbE, tb, 0, stream>>>(dst, src, bgh, gq2, E);
    // gz1b = b ⊙ ((a⊙(gq2@W2^T) ⊙ relu'(u)) @ W1^T)
    k_bwd_dense<<<gbN, tb, 0, stream>>>(gq2, z1, a_, b_, W1, b1, W2, gz1b, N);
    // dHdQ = gh + a ⊙ Agg^T(gz1b)
    k_scatter8 <<<gbE, tb, 0, stream>>>(dst, src, gz1b, r1, E);
    k_out      <<<gbN, tb, 0, stream>>>(gh, r1, a_, out, N);
}

// Round 2
// 743.070 us; speedup vs baseline: 5.6423x; 5.6423x over previous
//
#include <hip/hip_runtime.h>

#define DD 8
#define HH 256

// ============================ CSR construction ==============================

__global__ void k_count(const int* __restrict__ src, const int* __restrict__ dst,
                        int* __restrict__ cnt_out, int* __restrict__ cnt_in, int E) {
    int e = blockIdx.x * blockDim.x + threadIdx.x;
    if (e >= E) return;
    atomicAdd(&cnt_out[src[e]], 1);
    atomicAdd(&cnt_in[dst[e]], 1);
}

// phase 1: per-256-chunk exclusive scan; chunk totals to bsum. grid=(nblk,2)
__global__ void k_scan1(const int* __restrict__ cnt_in, const int* __restrict__ cnt_out,
                        int* __restrict__ start_in, int* __restrict__ start_out,
                        int* __restrict__ bsum, int nblk, int N) {
    const int dir = blockIdx.y;
    const int* cnt = dir ? cnt_out : cnt_in;
    int* start = dir ? start_out : start_in;
    int* bs = bsum + dir * nblk;
    __shared__ int s[256];
    int i = blockIdx.x * 256 + threadIdx.x;
    int v = (i < N) ? cnt[i] : 0;
    s[threadIdx.x] = v;
    __syncthreads();
    for (int off = 1; off < 256; off <<= 1) {
        int t = (threadIdx.x >= off) ? s[threadIdx.x - off] : 0;
        __syncthreads();
        s[threadIdx.x] += t;
        __syncthreads();
    }
    if (i < N) start[i] = s[threadIdx.x] - v;   // exclusive
    if (threadIdx.x == 255) bs[blockIdx.x] = s[255];
}

// phase 2: scan the chunk totals (nblk <= 512). grid=(2), block=512
__global__ void k_scan2(int* __restrict__ bsum, int nblk,
                        int* __restrict__ start_in, int* __restrict__ start_out, int N) {
    const int dir = blockIdx.x;
    int* bs = bsum + dir * nblk;
    __shared__ int s[512];
    int v = (threadIdx.x < nblk) ? bs[threadIdx.x] : 0;
    s[threadIdx.x] = v;
    __syncthreads();
    for (int off = 1; off < 512; off <<= 1) {
        int t = (threadIdx.x >= off) ? s[threadIdx.x - off] : 0;
        __syncthreads();
        s[threadIdx.x] += t;
        __syncthreads();
    }
    if (threadIdx.x < nblk) bs[threadIdx.x] = s[threadIdx.x] - v;   // exclusive
    if (threadIdx.x == 511) (dir ? start_out : start_in)[N] = s[511];  // total E
}

// phase 3: add chunk offsets. grid=(nblk,2)
__global__ void k_scan3(int* __restrict__ start_in, int* __restrict__ start_out,
                        const int* __restrict__ bsum, int nblk, int N) {
    const int dir = blockIdx.y;
    int* start = dir ? start_out : start_in;
    const int* bs = bsum + dir * nblk;
    int i = blockIdx.x * 256 + threadIdx.x;
    if (i < N) start[i] += bs[blockIdx.x];
}

// fill CSR neighbor lists (cursor arrays = cnt buffers, re-initialized in k_prep)
__global__ void k_place(const int* __restrict__ src, const int* __restrict__ dst,
                        int* __restrict__ cur_in, int* __restrict__ cur_out,
                        int* __restrict__ csr_in, int* __restrict__ csr_out, int E) {
    int e = blockIdx.x * blockDim.x + threadIdx.x;
    if (e >= E) return;
    int s = src[e], d = dst[e];
    int pi = atomicAdd(&cur_in[d], 1);  csr_in[pi]  = s;   // in-CSR stores src nbr
    int po = atomicAdd(&cur_out[s], 1); csr_out[po] = d;   // out-CSR stores dst nbr
}

// ===================== per-node prep (norms, masses, dHdP) ==================

__global__ void k_prep(const float* __restrict__ q, const float* __restrict__ p,
                       const float* __restrict__ M,
                       const int* __restrict__ start_in, const int* __restrict__ start_out,
                       int* __restrict__ cur_in, int* __restrict__ cur_out,
                       float* __restrict__ a, float* __restrict__ b,
                       float* __restrict__ md, float* __restrict__ qn,
                       float* __restrict__ out, int N) {
    int v = blockIdx.x * blockDim.x + threadIdx.x;
    if (v >= N) return;
    int si = start_in[v], so = start_out[v];
    cur_in[v] = si; cur_out[v] = so;                 // init place cursors
    float din  = (float)(start_in[v + 1] - si);
    float dout = (float)(start_out[v + 1] - so);
    float av = 1.0f / sqrtf(dout > 0.f ? dout : 1.f);   // norm_src
    float bv = 1.0f / sqrtf(din  > 0.f ? din  : 1.f);   // norm_dst
    a[v] = av; b[v] = bv;
#pragma unroll
    for (int d = 0; d < DD; d++) {
        float m = M[(size_t)v * DD * DD + d * (DD + 1)];
        md[(size_t)v * DD + d] = m;
        qn[(size_t)v * DD + d] = av * q[(size_t)v * DD + d];
        out[(size_t)v * 2 * DD + DD + d] = p[(size_t)v * DD + d] / m;  // dHdP
    }
}

// ================= atomic-free gathers: 8 lanes per node ====================

// y[v][d] = sum over csr range of x[nbr][d]
__global__ void k_gather8(const int* __restrict__ start, const int* __restrict__ csr,
                          const float* __restrict__ x, float* __restrict__ y, int N) {
    int t = blockIdx.x * blockDim.x + threadIdx.x;
    int v = t >> 3, d = t & 7;
    if (v >= N) return;
    int e0 = start[v], e1 = start[v + 1];
    float s = 0.f;
    int e = e0;
    for (; e + 1 < e1; e += 2) {
        int u0 = csr[e], u1 = csr[e + 1];
        s += x[(size_t)u0 * DD + d] + x[(size_t)u1 * DD + d];
    }
    if (e < e1) s += x[(size_t)csr[e] * DD + d];
    y[(size_t)v * DD + d] = s;
}

// h[v] = b[v] * (sum over in-CSR of ya[nbr]) + b2 + q[v]
__global__ void k_h_agg(const int* __restrict__ start, const int* __restrict__ csr,
                        const float* __restrict__ ya, const float* __restrict__ b,
                        const float* __restrict__ q, const float* __restrict__ b2,
                        float* __restrict__ h, int N) {
    int t = blockIdx.x * blockDim.x + threadIdx.x;
    int v = t >> 3, d = t & 7;
    if (v >= N) return;
    int e0 = start[v], e1 = start[v + 1];
    float s = 0.f;
    int e = e0;
    for (; e + 1 < e1; e += 2) {
        int u0 = csr[e], u1 = csr[e + 1];
        s += ya[(size_t)u0 * DD + d] + ya[(size_t)u1 * DD + d];
    }
    if (e < e1) s += ya[(size_t)csr[e] * DD + d];
    h[(size_t)v * DD + d] = fmaf(b[v], s, b2[d] + q[(size_t)v * DD + d]);
}

// gravity gradient wrt h, symmetric per-node form:
// gh[v] = sum over ALL incident edges of c_e * (h[v] - h[nbr]),
// c_e = -0.5*g*dot(md[v],md[nbr]) / ||h[v]-h[nbr]||^3   (symmetric in endpoints)
__global__ void k_gh(const int* __restrict__ start_in, const int* __restrict__ csr_in,
                     const int* __restrict__ start_out, const int* __restrict__ csr_out,
                     const float* __restrict__ h, const float* __restrict__ md,
                     const float* __restrict__ b, const float* __restrict__ grav,
                     float* __restrict__ gh, float* __restrict__ bgh, int N) {
    int t = blockIdx.x * blockDim.x + threadIdx.x;
    int v = t >> 3, d = t & 7;
    if (v >= N) return;
    float hv = h[(size_t)v * DD + d];
    float mv = md[(size_t)v * DD + d];
    float coef = -0.5f * grav[0];
    float acc = 0.f;
#pragma unroll
    for (int dir = 0; dir < 2; dir++) {
        const int* start = dir ? start_out : start_in;
        const int* csr   = dir ? csr_out   : csr_in;
        int e1 = start[v + 1];
        for (int e = start[v]; e < e1; e++) {
            int u = csr[e];
            float hu = h[(size_t)u * DD + d];
            float mu = md[(size_t)u * DD + d];
            float dif = hv - hu;
            float e2 = dif * dif;
            float S  = mv * mu;
            e2 += __shfl_xor(e2, 1); S += __shfl_xor(S, 1);
            e2 += __shfl_xor(e2, 2); S += __shfl_xor(S, 2);
            e2 += __shfl_xor(e2, 4); S += __shfl_xor(S, 4);
            float c = coef * S / (e2 * sqrtf(e2));
            acc = fmaf(c, dif, acc);
        }
    }
    gh[(size_t)v * DD + d] = acc;
    bgh[(size_t)v * DD + d] = b[v] * acc;
}

// out[:, :D] = gh + a * (sum over out-CSR of gz1b[nbr])
__global__ void k_out_agg(const int* __restrict__ start, const int* __restrict__ csr,
                          const float* __restrict__ gz1b, const float* __restrict__ gh,
                          const float* __restrict__ a, float* __restrict__ out, int N) {
    int t = blockIdx.x * blockDim.x + threadIdx.x;
    int v = t >> 3, d = t & 7;
    if (v >= N) return;
    int e0 = start[v], e1 = start[v + 1];
    float s = 0.f;
    int e = e0;
    for (; e + 1 < e1; e += 2) {
        int u0 = csr[e], u1 = csr[e + 1];
        s += gz1b[(size_t)u0 * DD + d] + gz1b[(size_t)u1 * DD + d];
    }
    if (e < e1) s += gz1b[(size_t)csr[e] * DD + d];
    out[(size_t)v * 2 * DD + d] = fmaf(a[v], s, gh[(size_t)v * DD + d]);
}

// ========================= dense MLP node kernels ===========================
// W1 stored transposed in LDS so both W1 and W2 rows are float4-readable.

__launch_bounds__(256)
__global__ void k_fwd_dense(const float* __restrict__ agg1, const float* __restrict__ a,
                            const float* __restrict__ b,
                            const float* __restrict__ W1, const float* __restrict__ b1,
                            const float* __restrict__ W2,
                            float* __restrict__ z1out, float* __restrict__ ya, int N) {
    __shared__ float sW1t[HH * DD];  // [j][d] = W1[d][j]
    __shared__ float sW2[HH * DD];   // [j][d]
    __shared__ float sb1[HH];
    for (int i = threadIdx.x; i < HH * DD; i += blockDim.x) {
        sW1t[i] = W1[(i & 7) * HH + (i >> 3)];
        sW2[i] = W2[i];
    }
    for (int i = threadIdx.x; i < HH; i += blockDim.x) sb1[i] = b1[i];
    __syncthreads();
    int v = blockIdx.x * blockDim.x + threadIdx.x;
    if (v >= N) return;
    float z[DD], y[DD];
    float bv = b[v];
#pragma unroll
    for (int d = 0; d < DD; d++) { z[d] = bv * agg1[(size_t)v * DD + d]; y[d] = 0.f; }
#pragma unroll
    for (int d = 0; d < DD; d++) z1out[(size_t)v * DD + d] = z[d];
    for (int j = 0; j < HH; j++) {
        const float4* w1r = (const float4*)(sW1t + j * DD);
        const float4* w2r = (const float4*)(sW2 + j * DD);
        float4 wa = w1r[0], wb = w1r[1];
        float u = sb1[j];
        u = fmaf(z[0], wa.x, u); u = fmaf(z[1], wa.y, u);
        u = fmaf(z[2], wa.z, u); u = fmaf(z[3], wa.w, u);
        u = fmaf(z[4], wb.x, u); u = fmaf(z[5], wb.y, u);
        u = fmaf(z[6], wb.z, u); u = fmaf(z[7], wb.w, u);
        float hh = fmaxf(u, 0.f);
        float4 va = w2r[0], vb = w2r[1];
        y[0] = fmaf(hh, va.x, y[0]); y[1] = fmaf(hh, va.y, y[1]);
        y[2] = fmaf(hh, va.z, y[2]); y[3] = fmaf(hh, va.w, y[3]);
        y[4] = fmaf(hh, vb.x, y[4]); y[5] = fmaf(hh, vb.y, y[5]);
        y[6] = fmaf(hh, vb.z, y[6]); y[7] = fmaf(hh, vb.w, y[7]);
    }
    float av = a[v];
#pragma unroll
    for (int d = 0; d < DD; d++) ya[(size_t)v * DD + d] = av * y[d];
}

__launch_bounds__(256)
__global__ void k_bwd_dense(const float* __restrict__ gq2, const float* __restrict__ z1,
                            const float* __restrict__ a, const float* __restrict__ b,
                            const float* __restrict__ W1, const float* __restrict__ b1,
                            const float* __restrict__ W2,
                            float* __restrict__ gz1b, int N) {
    __shared__ float sW1t[HH * DD];
    __shared__ float sW2[HH * DD];
    __shared__ float sb1[HH];
    for (int i = threadIdx.x; i < HH * DD; i += blockDim.x) {
        sW1t[i] = W1[(i & 7) * HH + (i >> 3)];
        sW2[i] = W2[i];
    }
    for (int i = threadIdx.x; i < HH; i += blockDim.x) sb1[i] = b1[i];
    __syncthreads();
    int v = blockIdx.x * blockDim.x + threadIdx.x;
    if (v >= N) return;
    float z[DD], gq[DD], gz[DD];
#pragma unroll
    for (int d = 0; d < DD; d++) {
        z[d]  = z1[(size_t)v * DD + d];
        gq[d] = gq2[(size_t)v * DD + d];
        gz[d] = 0.f;
    }
    float av = a[v];
    for (int j = 0; j < HH; j++) {
        const float4* w1r = (const float4*)(sW1t + j * DD);
        const float4* w2r = (const float4*)(sW2 + j * DD);
        float4 wa = w1r[0], wb = w1r[1];
        float u = sb1[j];
        u = fmaf(z[0], wa.x, u); u = fmaf(z[1], wa.y, u);
        u = fmaf(z[2], wa.z, u); u = fmaf(z[3], wa.w, u);
        u = fmaf(z[4], wb.x, u); u = fmaf(z[5], wb.y, u);
        u = fmaf(z[6], wb.z, u); u = fmaf(z[7], wb.w, u);
        float4 va = w2r[0], vb = w2r[1];
        float g = gq[0] * va.x + gq[1] * va.y + gq[2] * va.z + gq[3] * va.w
                + gq[4] * vb.x + gq[5] * vb.y + gq[6] * vb.z + gq[7] * vb.w;
        g = (u > 0.f) ? av * g : 0.f;
        gz[0] = fmaf(g, wa.x, gz[0]); gz[1] = fmaf(g, wa.y, gz[1]);
        gz[2] = fmaf(g, wa.z, gz[2]); gz[3] = fmaf(g, wa.w, gz[3]);
        gz[4] = fmaf(g, wb.x, gz[4]); gz[5] = fmaf(g, wb.y, gz[5]);
        gz[6] = fmaf(g, wb.z, gz[6]); gz[7] = fmaf(g, wb.w, gz[7]);
    }
    float bv = b[v];
#pragma unroll
    for (int d = 0; d < DD; d++) gz1b[(size_t)v * DD + d] = bv * gz[d];
}

// ============================== launch =====================================

extern "C" void kernel_launch(void* const* d_in, const int* in_sizes, int n_in,
                              void* d_out, int out_size, void* d_ws, size_t ws_size,
                              hipStream_t stream) {
    const float* q    = (const float*)d_in[0];
    const float* p    = (const float*)d_in[1];
    const float* M    = (const float*)d_in[2];
    const int*   src  = (const int*)d_in[3];
    const int*   dst  = (const int*)d_in[4];
    const float* W1   = (const float*)d_in[5];
    const float* b1   = (const float*)d_in[6];
    const float* W2   = (const float*)d_in[7];
    const float* b2   = (const float*)d_in[8];
    const float* grav = (const float*)d_in[9];
    float* out = (float*)d_out;

    int N = in_sizes[0] / DD;
    int E = in_sizes[3];
    size_t n = (size_t)N;

    // ---- float region (58N floats = 23.2 MB) ----
    float* ws   = (float*)d_ws;
    float* a_   = ws;             // N
    float* b_   = ws + n;         // N
    float* md   = ws + 2  * n;    // 8N
    float* qn   = ws + 10 * n;    // 8N   (reused as bgh)
    float* agg1 = ws + 18 * n;    // 8N   (reused as gq2)
    float* z1   = ws + 26 * n;    // 8N
    float* ya   = ws + 34 * n;    // 8N   (reused as gz1b)
    float* h    = ws + 42 * n;    // 8N
    float* gh   = ws + 50 * n;    // 8N
    float* bgh  = qn;
    float* gq2  = agg1;
    float* gz1b = ya;

    // ---- int region (~14.4 MB) ----
    int nblk = (N + 255) / 256;
    int* iw        = (int*)(ws + 58 * n);
    int* cnt_in    = iw;                       // N (then reused as cursor)
    int* cnt_out   = iw + n;                   // N (then reused as cursor)
    int* start_in  = iw + 2 * n;               // N+1
    int* start_out = iw + 3 * n + 1;           // N+1
    int* bsum      = iw + 4 * n + 2;           // 2*nblk
    int* csr_in    = iw + 4 * n + 2 + 2 * nblk;        // E
    int* csr_out   = iw + 4 * n + 2 + 2 * nblk + E;    // E

    // zero only the count arrays
    hipMemsetAsync(cnt_in, 0, 2 * n * sizeof(int), stream);

    const int tb = 256;
    int gbE = (E + tb - 1) / tb;
    int gbN = (N + tb - 1) / tb;
    int gb8 = (int)((8 * n + tb - 1) / tb);

    // CSR build
    k_count<<<gbE, tb, 0, stream>>>(src, dst, cnt_out, cnt_in, E);
    k_scan1<<<dim3(nblk, 2), tb, 0, stream>>>(cnt_in, cnt_out, start_in, start_out, bsum, nblk, N);
    k_scan2<<<2, 512, 0, stream>>>(bsum, nblk, start_in, start_out, N);
    k_scan3<<<dim3(nblk, 2), tb, 0, stream>>>(start_in, start_out, bsum, nblk, N);
    k_prep <<<gbN, tb, 0, stream>>>(q, p, M, start_in, start_out, cnt_in, cnt_out,
                                    a_, b_, md, qn, out, N);
    k_place<<<gbE, tb, 0, stream>>>(src, dst, cnt_in, cnt_out, csr_in, csr_out, E);

    // forward: z1 = b ⊙ AggIn(a ⊙ q); ya = a ⊙ (relu(z1@W1+b1)@W2)
    k_gather8  <<<gb8, tb, 0, stream>>>(start_in, csr_in, qn, agg1, N);
    k_fwd_dense<<<gbN, tb, 0, stream>>>(agg1, a_, b_, W1, b1, W2, z1, ya, N);
    // h = b ⊙ AggIn(ya) + b2 + q
    k_h_agg    <<<gb8, tb, 0, stream>>>(start_in, csr_in, ya, b_, q, b2, h, N);
    // gravity gradient (symmetric per-node, no atomics)
    k_gh       <<<gb8, tb, 0, stream>>>(start_in, csr_in, start_out, csr_out,
                                        h, md, b_, grav, gh, bgh, N);
    // gq2 = AggOut(bgh); gz1b = b ⊙ ((a⊙(gq2@W2^T) ⊙ relu') @ W1^T)
    k_gather8  <<<gb8, tb, 0, stream>>>(start_out, csr_out, bgh, gq2, N);
    k_bwd_dense<<<gbN, tb, 0, stream>>>(gq2, z1, a_, b_, W1, b1, W2, gz1b, N);
    // dHdQ = gh + a ⊙ AggOut(gz1b)
    k_out_agg  <<<gb8, tb, 0, stream>>>(start_out, csr_out, gz1b, gh, a_, out, N);
}

// Round 3
// 441.256 us; speedup vs baseline: 9.5016x; 1.6840x over previous
//
#include <hip/hip_runtime.h>

#define DD 8
#define HH 256
#define CH 8192          // edges per chunk in coarse/partition kernels
#define PAYBITS 17       // N <= 131072
#define PAYMASK 0x1FFFF

// ============================ CSR construction ==============================
// Bucketed counting sort: coarse bucket = node >> 9 (512 ids/bucket),
// fine bin = node & 511. No global atomics on node-sized arrays.

__global__ void k_coarse(const int* __restrict__ src, const int* __restrict__ dst,
                         int* __restrict__ gHistIn, int* __restrict__ gHistOut,
                         int NB, int E) {
    __shared__ int hIn[256], hOut[256];
    if (threadIdx.x < 256) { hIn[threadIdx.x] = 0; hOut[threadIdx.x] = 0; }
    __syncthreads();
    int lo = blockIdx.x * CH;
    int hi = min(lo + CH, E);
    for (int i = lo + threadIdx.x; i < hi; i += blockDim.x) {
        atomicAdd(&hIn[dst[i] >> 9], 1);
        atomicAdd(&hOut[src[i] >> 9], 1);
    }
    __syncthreads();
    if (threadIdx.x < NB) {
        int ci = hIn[threadIdx.x], co = hOut[threadIdx.x];
        if (ci) atomicAdd(&gHistIn[threadIdx.x], ci);
        if (co) atomicAdd(&gHistOut[threadIdx.x], co);
    }
}

// single-block exclusive scan of both coarse histograms (NB <= 256)
__global__ void k_cscan(const int* __restrict__ gHistIn, const int* __restrict__ gHistOut,
                        int* __restrict__ cStartIn, int* __restrict__ cStartOut,
                        int* __restrict__ cCurIn, int* __restrict__ cCurOut,
                        int NB, int E) {
    __shared__ int s[256];
#pragma unroll
    for (int dir = 0; dir < 2; dir++) {
        const int* gh = dir ? gHistOut : gHistIn;
        int* cs = dir ? cStartOut : cStartIn;
        int* cc = dir ? cCurOut : cCurIn;
        int v = (threadIdx.x < NB) ? gh[threadIdx.x] : 0;
        s[threadIdx.x] = v;
        __syncthreads();
        for (int off = 1; off < 256; off <<= 1) {
            int t = (threadIdx.x >= off) ? s[threadIdx.x - off] : 0;
            __syncthreads();
            s[threadIdx.x] += t;
            __syncthreads();
        }
        if (threadIdx.x < NB) {
            int ex = s[threadIdx.x] - v;
            cs[threadIdx.x] = ex;
            cc[threadIdx.x] = ex;
        }
        if (threadIdx.x == 0) cs[NB] = E;
        __syncthreads();
    }
}

// partition edges into coarse buckets; packed entry = (node&511)<<17 | payload
__global__ void k_partition(const int* __restrict__ key, const int* __restrict__ pay,
                            int* __restrict__ cCur, int* __restrict__ P,
                            int NB, int E) {
    __shared__ int h[256];
    if (threadIdx.x < 256) h[threadIdx.x] = 0;
    __syncthreads();
    int lo = blockIdx.x * CH;
    int hi = min(lo + CH, E);
    for (int i = lo + threadIdx.x; i < hi; i += blockDim.x)
        atomicAdd(&h[key[i] >> 9], 1);
    __syncthreads();
    if (threadIdx.x < NB) {
        int c = h[threadIdx.x];
        h[threadIdx.x] = c ? atomicAdd(&cCur[threadIdx.x], c) : 0;
    }
    __syncthreads();
    for (int i = lo + threadIdx.x; i < hi; i += blockDim.x) {
        int k = key[i];
        int pos = atomicAdd(&h[k >> 9], 1);
        P[pos] = ((k & 511) << PAYBITS) | pay[i];
    }
}

// one block per coarse bucket: fine histogram + scan -> start[], then scatter
__launch_bounds__(512)
__global__ void k_fine(const int* __restrict__ cStart, const int* __restrict__ P,
                       int* __restrict__ start, int* __restrict__ csr, int N) {
    __shared__ int cnt[512], scn[512];
    int b = blockIdx.x;
    int lo = cStart[b], hi = cStart[b + 1];
    cnt[threadIdx.x] = 0;
    __syncthreads();
    for (int i = lo + threadIdx.x; i < hi; i += 512)
        atomicAdd(&cnt[P[i] >> PAYBITS], 1);
    __syncthreads();
    int own = cnt[threadIdx.x];
    scn[threadIdx.x] = own;
    __syncthreads();
    for (int off = 1; off < 512; off <<= 1) {
        int t = (threadIdx.x >= off) ? scn[threadIdx.x - off] : 0;
        __syncthreads();
        scn[threadIdx.x] += t;
        __syncthreads();
    }
    int base = lo + scn[threadIdx.x] - own;
    int node = (b << 9) + threadIdx.x;
    if (node < N) start[node] = base;
    cnt[threadIdx.x] = base;   // reuse as cursor
    __syncthreads();
    for (int i = lo + threadIdx.x; i < hi; i += 512) {
        int p = P[i];
        int pos = atomicAdd(&cnt[p >> PAYBITS], 1);
        csr[pos] = p & PAYMASK;
    }
}

// ===================== per-node prep (norms, masses, dHdP) ==================
// also writes the start[N]=E sentinels (thread 0) so later kernels can read
// start[v+1] uniformly; k_prep itself clamps v+1 reads for v==N-1.

__global__ void k_prep(const float* __restrict__ q, const float* __restrict__ p,
                       const float* __restrict__ M,
                       int* __restrict__ start_in, int* __restrict__ start_out,
                       float* __restrict__ a, float* __restrict__ b,
                       float* __restrict__ md, float* __restrict__ qn,
                       float* __restrict__ out, int N, int E) {
    int v = blockIdx.x * blockDim.x + threadIdx.x;
    if (blockIdx.x == 0 && threadIdx.x == 0) { start_in[N] = E; start_out[N] = E; }
    if (v >= N) return;
    int ei1 = (v + 1 < N) ? start_in[v + 1]  : E;
    int eo1 = (v + 1 < N) ? start_out[v + 1] : E;
    float din  = (float)(ei1 - start_in[v]);
    float dout = (float)(eo1 - start_out[v]);
    float av = 1.0f / sqrtf(dout > 0.f ? dout : 1.f);   // norm_src
    float bv = 1.0f / sqrtf(din  > 0.f ? din  : 1.f);   // norm_dst
    a[v] = av; b[v] = bv;
#pragma unroll
    for (int d = 0; d < DD; d++) {
        float m = M[(size_t)v * DD * DD + d * (DD + 1)];
        md[(size_t)v * DD + d] = m;
        qn[(size_t)v * DD + d] = av * q[(size_t)v * DD + d];
        out[(size_t)v * 2 * DD + DD + d] = p[(size_t)v * DD + d] / m;  // dHdP
    }
}

// ================= atomic-free gathers: 8 lanes per node ====================

__global__ void k_gather8(const int* __restrict__ start, const int* __restrict__ csr,
                          const float* __restrict__ x, float* __restrict__ y, int N) {
    int t = blockIdx.x * blockDim.x + threadIdx.x;
    int v = t >> 3, d = t & 7;
    if (v >= N) return;
    int e0 = start[v], e1 = start[v + 1];
    float s = 0.f;
    int e = e0;
    for (; e + 1 < e1; e += 2) {
        int u0 = csr[e], u1 = csr[e + 1];
        s += x[(size_t)u0 * DD + d] + x[(size_t)u1 * DD + d];
    }
    if (e < e1) s += x[(size_t)csr[e] * DD + d];
    y[(size_t)v * DD + d] = s;
}

__global__ void k_h_agg(const int* __restrict__ start, const int* __restrict__ csr,
                        const float* __restrict__ ya, const float* __restrict__ b,
                        const float* __restrict__ q, const float* __restrict__ b2,
                        float* __restrict__ h, int N) {
    int t = blockIdx.x * blockDim.x + threadIdx.x;
    int v = t >> 3, d = t & 7;
    if (v >= N) return;
    int e0 = start[v], e1 = start[v + 1];
    float s = 0.f;
    int e = e0;
    for (; e + 1 < e1; e += 2) {
        int u0 = csr[e], u1 = csr[e + 1];
        s += ya[(size_t)u0 * DD + d] + ya[(size_t)u1 * DD + d];
    }
    if (e < e1) s += ya[(size_t)csr[e] * DD + d];
    h[(size_t)v * DD + d] = fmaf(b[v], s, b2[d] + q[(size_t)v * DD + d]);
}

__global__ void k_gh(const int* __restrict__ start_in, const int* __restrict__ csr_in,
                     const int* __restrict__ start_out, const int* __restrict__ csr_out,
                     const float* __restrict__ h, const float* __restrict__ md,
                     const float* __restrict__ b, const float* __restrict__ grav,
                     float* __restrict__ gh, float* __restrict__ bgh, int N) {
    int t = blockIdx.x * blockDim.x + threadIdx.x;
    int v = t >> 3, d = t & 7;
    if (v >= N) return;
    float hv = h[(size_t)v * DD + d];
    float mv = md[(size_t)v * DD + d];
    float coef = -0.5f * grav[0];
    float acc = 0.f;
#pragma unroll
    for (int dir = 0; dir < 2; dir++) {
        const int* start = dir ? start_out : start_in;
        const int* csr   = dir ? csr_out   : csr_in;
        int e1 = start[v + 1];
        for (int e = start[v]; e < e1; e++) {
            int u = csr[e];
            float hu = h[(size_t)u * DD + d];
            float mu = md[(size_t)u * DD + d];
            float dif = hv - hu;
            float e2 = dif * dif;
            float S  = mv * mu;
            e2 += __shfl_xor(e2, 1); S += __shfl_xor(S, 1);
            e2 += __shfl_xor(e2, 2); S += __shfl_xor(S, 2);
            e2 += __shfl_xor(e2, 4); S += __shfl_xor(S, 4);
            float c = coef * S / (e2 * sqrtf(e2));
            acc = fmaf(c, dif, acc);
        }
    }
    gh[(size_t)v * DD + d] = acc;
    bgh[(size_t)v * DD + d] = b[v] * acc;
}

__global__ void k_out_agg(const int* __restrict__ start, const int* __restrict__ csr,
                          const float* __restrict__ gz1b, const float* __restrict__ gh,
                          const float* __restrict__ a, float* __restrict__ out, int N) {
    int t = blockIdx.x * blockDim.x + threadIdx.x;
    int v = t >> 3, d = t & 7;
    if (v >= N) return;
    int e0 = start[v], e1 = start[v + 1];
    float s = 0.f;
    int e = e0;
    for (; e + 1 < e1; e += 2) {
        int u0 = csr[e], u1 = csr[e + 1];
        s += gz1b[(size_t)u0 * DD + d] + gz1b[(size_t)u1 * DD + d];
    }
    if (e < e1) s += gz1b[(size_t)csr[e] * DD + d];
    out[(size_t)v * 2 * DD + d] = fmaf(a[v], s, gh[(size_t)v * DD + d]);
}

// ========================= dense MLP node kernels ===========================

__launch_bounds__(256)
__global__ void k_fwd_dense(const float* __restrict__ agg1, const float* __restrict__ a,
                            const float* __restrict__ b,
                            const float* __restrict__ W1, const float* __restrict__ b1,
                            const float* __restrict__ W2,
                            float* __restrict__ z1out, float* __restrict__ ya, int N) {
    __shared__ float sW1t[HH * DD];
    __shared__ float sW2[HH * DD];
    __shared__ float sb1[HH];
    for (int i = threadIdx.x; i < HH * DD; i += blockDim.x) {
        sW1t[i] = W1[(i & 7) * HH + (i >> 3)];
        sW2[i] = W2[i];
    }
    for (int i = threadIdx.x; i < HH; i += blockDim.x) sb1[i] = b1[i];
    __syncthreads();
    int v = blockIdx.x * blockDim.x + threadIdx.x;
    if (v >= N) return;
    float z[DD], y[DD];
    float bv = b[v];
#pragma unroll
    for (int d = 0; d < DD; d++) { z[d] = bv * agg1[(size_t)v * DD + d]; y[d] = 0.f; }
#pragma unroll
    for (int d = 0; d < DD; d++) z1out[(size_t)v * DD + d] = z[d];
    for (int j = 0; j < HH; j++) {
        const float4* w1r = (const float4*)(sW1t + j * DD);
        const float4* w2r = (const float4*)(sW2 + j * DD);
        float4 wa = w1r[0], wb = w1r[1];
        float u = sb1[j];
        u = fmaf(z[0], wa.x, u); u = fmaf(z[1], wa.y, u);
        u = fmaf(z[2], wa.z, u); u = fmaf(z[3], wa.w, u);
        u = fmaf(z[4], wb.x, u); u = fmaf(z[5], wb.y, u);
        u = fmaf(z[6], wb.z, u); u = fmaf(z[7], wb.w, u);
        float hh = fmaxf(u, 0.f);
        float4 va = w2r[0], vb = w2r[1];
        y[0] = fmaf(hh, va.x, y[0]); y[1] = fmaf(hh, va.y, y[1]);
        y[2] = fmaf(hh, va.z, y[2]); y[3] = fmaf(hh, va.w, y[3]);
        y[4] = fmaf(hh, vb.x, y[4]); y[5] = fmaf(hh, vb.y, y[5]);
        y[6] = fmaf(hh, vb.z, y[6]); y[7] = fmaf(hh, vb.w, y[7]);
    }
    float av = a[v];
#pragma unroll
    for (int d = 0; d < DD; d++) ya[(size_t)v * DD + d] = av * y[d];
}

__launch_bounds__(256)
__global__ void k_bwd_dense(const float* __restrict__ gq2, const float* __restrict__ z1,
                            const float* __restrict__ a, const float* __restrict__ b,
                            const float* __restrict__ W1, const float* __restrict__ b1,
                            const float* __restrict__ W2,
                            float* __restrict__ gz1b, int N) {
    __shared__ float sW1t[HH * DD];
    __shared__ float sW2[HH * DD];
    __shared__ float sb1[HH];
    for (int i = threadIdx.x; i < HH * DD; i += blockDim.x) {
        sW1t[i] = W1[(i & 7) * HH + (i >> 3)];
        sW2[i] = W2[i];
    }
    for (int i = threadIdx.x; i < HH; i += blockDim.x) sb1[i] = b1[i];
    __syncthreads();
    int v = blockIdx.x * blockDim.x + threadIdx.x;
    if (v >= N) return;
    float z[DD], gq[DD], gz[DD];
#pragma unroll
    for (int d = 0; d < DD; d++) {
        z[d]  = z1[(size_t)v * DD + d];
        gq[d] = gq2[(size_t)v * DD + d];
        gz[d] = 0.f;
    }
    float av = a[v];
    for (int j = 0; j < HH; j++) {
        const float4* w1r = (const float4*)(sW1t + j * DD);
        const float4* w2r = (const float4*)(sW2 + j * DD);
        float4 wa = w1r[0], wb = w1r[1];
        float u = sb1[j];
        u = fmaf(z[0], wa.x, u); u = fmaf(z[1], wa.y, u);
        u = fmaf(z[2], wa.z, u); u = fmaf(z[3], wa.w, u);
        u = fmaf(z[4], wb.x, u); u = fmaf(z[5], wb.y, u);
        u = fmaf(z[6], wb.z, u); u = fmaf(z[7], wb.w, u);
        float4 va = w2r[0], vb = w2r[1];
        float g = gq[0] * va.x + gq[1] * va.y + gq[2] * va.z + gq[3] * va.w
                + gq[4] * vb.x + gq[5] * vb.y + gq[6] * vb.z + gq[7] * vb.w;
        g = (u > 0.f) ? av * g : 0.f;
        gz[0] = fmaf(g, wa.x, gz[0]); gz[1] = fmaf(g, wa.y, gz[1]);
        gz[2] = fmaf(g, wa.z, gz[2]); gz[3] = fmaf(g, wa.w, gz[3]);
        gz[4] = fmaf(g, wb.x, gz[4]); gz[5] = fmaf(g, wb.y, gz[5]);
        gz[6] = fmaf(g, wb.z, gz[6]); gz[7] = fmaf(g, wb.w, gz[7]);
    }
    float bv = b[v];
#pragma unroll
    for (int d = 0; d < DD; d++) gz1b[(size_t)v * DD + d] = bv * gz[d];
}

// ============================== launch =====================================

extern "C" void kernel_launch(void* const* d_in, const int* in_sizes, int n_in,
                              void* d_out, int out_size, void* d_ws, size_t ws_size,
                              hipStream_t stream) {
    const float* q    = (const float*)d_in[0];
    const float* p    = (const float*)d_in[1];
    const float* M    = (const float*)d_in[2];
    const int*   src  = (const int*)d_in[3];
    const int*   dst  = (const int*)d_in[4];
    const float* W1   = (const float*)d_in[5];
    const float* b1   = (const float*)d_in[6];
    const float* W2   = (const float*)d_in[7];
    const float* b2   = (const float*)d_in[8];
    const float* grav = (const float*)d_in[9];
    float* out = (float*)d_out;

    int N = in_sizes[0] / DD;
    int E = in_sizes[3];
    size_t n = (size_t)N;
    int NB = (N + 511) >> 9;   // coarse buckets (<=256 for N<=131072)

    // ---- float region (58N floats) ----
    float* ws   = (float*)d_ws;
    float* a_   = ws;             // N
    float* b_   = ws + n;         // N
    float* md   = ws + 2  * n;    // 8N
    float* qn   = ws + 10 * n;    // 8N   (reused as bgh)
    float* agg1 = ws + 18 * n;    // 8N   (reused as gq2)
    float* z1   = ws + 26 * n;    // 8N
    float* ya   = ws + 34 * n;    // 8N   (reused as gz1b)
    float* h    = ws + 42 * n;    // 8N
    float* gh   = ws + 50 * n;    // 8N
    float* bgh  = qn;
    float* gq2  = agg1;
    float* gz1b = ya;

    // ---- int region ----
    int* iw        = (int*)(ws + 58 * n);
    int* csr_in    = iw;                       // E
    int* csr_out   = iw + (size_t)E;           // E
    int* start_in  = iw + 2 * (size_t)E;       // N+1
    int* start_out = start_in + n + 1;         // N+1
    int* gHistIn   = start_out + n + 1;        // 256
    int* gHistOut  = gHistIn + 256;            // 256
    int* cStartIn  = gHistOut + 256;           // NB+1
    int* cStartOut = cStartIn + NB + 1;        // NB+1
    int* cCurIn    = cStartOut + NB + 1;       // NB
    int* cCurOut   = cCurIn + NB;              // NB
    int* iwEnd     = cCurOut + NB;
    // partition scratch (E ints): alias h/gh float region (dead during CSR build)
    int* P = (E <= 16 * (long long)n) ? (int*)(ws + 42 * n) : iwEnd;

    hipMemsetAsync(gHistIn, 0, 512 * sizeof(int), stream);

    const int tb = 256;
    int gbN = (N + tb - 1) / tb;
    int gb8 = (int)((8 * n + tb - 1) / tb);
    int gbC = (E + CH - 1) / CH;

    // CSR build (bucketed counting sort, both directions; P reused)
    k_coarse   <<<gbC, tb, 0, stream>>>(src, dst, gHistIn, gHistOut, NB, E);
    k_cscan    <<<1, 256, 0, stream>>>(gHistIn, gHistOut, cStartIn, cStartOut,
                                       cCurIn, cCurOut, NB, E);
    k_partition<<<gbC, tb, 0, stream>>>(dst, src, cCurIn, P, NB, E);
    k_fine     <<<NB, 512, 0, stream>>>(cStartIn, P, start_in, csr_in, N);
    k_partition<<<gbC, tb, 0, stream>>>(src, dst, cCurOut, P, NB, E);
    k_fine     <<<NB, 512, 0, stream>>>(cStartOut, P, start_out, csr_out, N);
    k_prep     <<<gbN, tb, 0, stream>>>(q, p, M, start_in, start_out,
                                        a_, b_, md, qn, out, N, E);

    // forward: z1 = b ⊙ AggIn(a ⊙ q); ya = a ⊙ (relu(z1@W1+b1)@W2)
    k_gather8  <<<gb8, tb, 0, stream>>>(start_in, csr_in, qn, agg1, N);
    k_fwd_dense<<<gbN, tb, 0, stream>>>(agg1, a_, b_, W1, b1, W2, z1, ya, N);
    // h = b ⊙ AggIn(ya) + b2 + q
    k_h_agg    <<<gb8, tb, 0, stream>>>(start_in, csr_in, ya, b_, q, b2, h, N);
    // gravity gradient (symmetric per-node, no atomics)
    k_gh       <<<gb8, tb, 0, stream>>>(start_in, csr_in, start_out, csr_out,
                                        h, md, b_, grav, gh, bgh, N);
    // gq2 = AggOut(bgh); gz1b = b ⊙ ((a⊙(gq2@W2^T) ⊙ relu') @ W1^T)
    k_gather8  <<<gb8, tb, 0, stream>>>(start_out, csr_out, bgh, gq2, N);
    k_bwd_dense<<<gbN, tb, 0, stream>>>(gq2, z1, a_, b_, W1, b1, W2, gz1b, N);
    // dHdQ = gh + a ⊙ AggOut(gz1b)
    k_out_agg  <<<gb8, tb, 0, stream>>>(start_out, csr_out, gz1b, gh, a_, out, N);
}

// Round 4
// 428.836 us; speedup vs baseline: 9.7768x; 1.0290x over previous
//
#include <hip/hip_runtime.h>

#define DD 8
#define HH 256
#define CH 8192          // edges per chunk in coarse/partition kernels
#define PAYBITS 17       // N <= 131072
#define PAYMASK 0x1FFFF

// ============================ CSR construction ==============================
// Bucketed counting sort: coarse bucket = node >> 9 (512 ids/bucket),
// fine bin = node & 511. No global atomics on node-sized arrays.

__global__ void k_coarse(const int* __restrict__ src, const int* __restrict__ dst,
                         int* __restrict__ gHistIn, int* __restrict__ gHistOut,
                         int NB, int E) {
    __shared__ int hIn[256], hOut[256];
    if (threadIdx.x < 256) { hIn[threadIdx.x] = 0; hOut[threadIdx.x] = 0; }
    __syncthreads();
    int lo = blockIdx.x * CH;
    int hi = min(lo + CH, E);
    for (int i = lo + threadIdx.x; i < hi; i += blockDim.x) {
        atomicAdd(&hIn[dst[i] >> 9], 1);
        atomicAdd(&hOut[src[i] >> 9], 1);
    }
    __syncthreads();
    if (threadIdx.x < NB) {
        int ci = hIn[threadIdx.x], co = hOut[threadIdx.x];
        if (ci) atomicAdd(&gHistIn[threadIdx.x], ci);
        if (co) atomicAdd(&gHistOut[threadIdx.x], co);
    }
}

// single-block exclusive scan of both coarse histograms (NB <= 256)
__global__ void k_cscan(const int* __restrict__ gHistIn, const int* __restrict__ gHistOut,
                        int* __restrict__ cStartIn, int* __restrict__ cStartOut,
                        int* __restrict__ cCurIn, int* __restrict__ cCurOut,
                        int NB, int E) {
    __shared__ int s[256];
#pragma unroll
    for (int dir = 0; dir < 2; dir++) {
        const int* gh = dir ? gHistOut : gHistIn;
        int* cs = dir ? cStartOut : cStartIn;
        int* cc = dir ? cCurOut : cCurIn;
        int v = (threadIdx.x < NB) ? gh[threadIdx.x] : 0;
        s[threadIdx.x] = v;
        __syncthreads();
        for (int off = 1; off < 256; off <<= 1) {
            int t = (threadIdx.x >= off) ? s[threadIdx.x - off] : 0;
            __syncthreads();
            s[threadIdx.x] += t;
            __syncthreads();
        }
        if (threadIdx.x < NB) {
            int ex = s[threadIdx.x] - v;
            cs[threadIdx.x] = ex;
            cc[threadIdx.x] = ex;
        }
        if (threadIdx.x == 0) cs[NB] = E;
        __syncthreads();
    }
}

// partition edges into coarse buckets; packed entry = (node&511)<<17 | payload
__global__ void k_partition(const int* __restrict__ key, const int* __restrict__ pay,
                            int* __restrict__ cCur, int* __restrict__ P,
                            int NB, int E) {
    __shared__ int h[256];
    if (threadIdx.x < 256) h[threadIdx.x] = 0;
    __syncthreads();
    int lo = blockIdx.x * CH;
    int hi = min(lo + CH, E);
    for (int i = lo + threadIdx.x; i < hi; i += blockDim.x)
        atomicAdd(&h[key[i] >> 9], 1);
    __syncthreads();
    if (threadIdx.x < NB) {
        int c = h[threadIdx.x];
        h[threadIdx.x] = c ? atomicAdd(&cCur[threadIdx.x], c) : 0;
    }
    __syncthreads();
    for (int i = lo + threadIdx.x; i < hi; i += blockDim.x) {
        int k = key[i];
        int pos = atomicAdd(&h[k >> 9], 1);
        P[pos] = ((k & 511) << PAYBITS) | pay[i];
    }
}

// one block per coarse bucket: fine histogram + scan -> start[], then scatter
__launch_bounds__(512)
__global__ void k_fine(const int* __restrict__ cStart, const int* __restrict__ P,
                       int* __restrict__ start, int* __restrict__ csr, int N) {
    __shared__ int cnt[512], scn[512];
    int b = blockIdx.x;
    int lo = cStart[b], hi = cStart[b + 1];
    cnt[threadIdx.x] = 0;
    __syncthreads();
    for (int i = lo + threadIdx.x; i < hi; i += 512)
        atomicAdd(&cnt[P[i] >> PAYBITS], 1);
    __syncthreads();
    int own = cnt[threadIdx.x];
    scn[threadIdx.x] = own;
    __syncthreads();
    for (int off = 1; off < 512; off <<= 1) {
        int t = (threadIdx.x >= off) ? scn[threadIdx.x - off] : 0;
        __syncthreads();
        scn[threadIdx.x] += t;
        __syncthreads();
    }
    int base = lo + scn[threadIdx.x] - own;
    int node = (b << 9) + threadIdx.x;
    if (node < N) start[node] = base;
    cnt[threadIdx.x] = base;   // reuse as cursor
    __syncthreads();
    for (int i = lo + threadIdx.x; i < hi; i += 512) {
        int p = P[i];
        int pos = atomicAdd(&cnt[p >> PAYBITS], 1);
        csr[pos] = p & PAYMASK;
    }
}

// ===================== per-node prep (norms, masses, dHdP) ==================
// writes mass diagonal into the interleaved hmd[v][16] struct (slots 8..15);
// slots 0..7 (h) are filled later by k_h_agg. Also writes start[N]=E sentinels.

__global__ void k_prep(const float* __restrict__ q, const float* __restrict__ p,
                       const float* __restrict__ M,
                       int* __restrict__ start_in, int* __restrict__ start_out,
                       float* __restrict__ a, float* __restrict__ b,
                       float* __restrict__ hmd, float* __restrict__ qn,
                       float* __restrict__ out, int N, int E) {
    int v = blockIdx.x * blockDim.x + threadIdx.x;
    if (blockIdx.x == 0 && threadIdx.x == 0) { start_in[N] = E; start_out[N] = E; }
    if (v >= N) return;
    int ei1 = (v + 1 < N) ? start_in[v + 1]  : E;
    int eo1 = (v + 1 < N) ? start_out[v + 1] : E;
    float din  = (float)(ei1 - start_in[v]);
    float dout = (float)(eo1 - start_out[v]);
    float av = 1.0f / sqrtf(dout > 0.f ? dout : 1.f);   // norm_src
    float bv = 1.0f / sqrtf(din  > 0.f ? din  : 1.f);   // norm_dst
    a[v] = av; b[v] = bv;
#pragma unroll
    for (int d = 0; d < DD; d++) {
        float m = M[(size_t)v * DD * DD + d * (DD + 1)];
        hmd[(size_t)v * 16 + 8 + d] = m;
        qn[(size_t)v * DD + d] = av * q[(size_t)v * DD + d];
        out[(size_t)v * 2 * DD + DD + d] = p[(size_t)v * DD + d] / m;  // dHdP
    }
}

// ================= gather + elementwise node kernels ========================

// h = b*AggIn(ya) + b2 + q, written into hmd slots 0..7 (unroll-4 gather)
__global__ void k_h_agg(const int* __restrict__ start, const int* __restrict__ csr,
                        const float* __restrict__ ya, const float* __restrict__ b,
                        const float* __restrict__ q, const float* __restrict__ b2,
                        float* __restrict__ hmd, int N) {
    int t = blockIdx.x * blockDim.x + threadIdx.x;
    int v = t >> 3, d = t & 7;
    if (v >= N) return;
    int e0 = start[v], e1 = start[v + 1];
    float s = 0.f;
    int e = e0;
    for (; e + 3 < e1; e += 4) {
        int u0 = csr[e], u1 = csr[e + 1], u2 = csr[e + 2], u3 = csr[e + 3];
        float x0 = ya[(size_t)u0 * DD + d], x1 = ya[(size_t)u1 * DD + d];
        float x2 = ya[(size_t)u2 * DD + d], x3 = ya[(size_t)u3 * DD + d];
        s += (x0 + x1) + (x2 + x3);
    }
    for (; e < e1; e++) s += ya[(size_t)csr[e] * DD + d];
    hmd[(size_t)v * 16 + d] = fmaf(b[v], s, b2[d] + q[(size_t)v * DD + d]);
}

// gravity gradient wrt h, symmetric per-node form, interleaved hmd reads:
// gh[v] = sum over ALL incident edges of c_e * (h[v]-h[nbr]),
// c_e = -0.5*g*dot(md[v],md[nbr]) / ||h[v]-h[nbr]||^3   (symmetric)
__global__ void k_gh(const int* __restrict__ start_in, const int* __restrict__ csr_in,
                     const int* __restrict__ start_out, const int* __restrict__ csr_out,
                     const float* __restrict__ hmd,
                     const float* __restrict__ b, const float* __restrict__ grav,
                     float* __restrict__ gh, float* __restrict__ bgh, int N) {
    int t = blockIdx.x * blockDim.x + threadIdx.x;
    int v = t >> 3, d = t & 7;
    if (v >= N) return;
    float hv = hmd[(size_t)v * 16 + d];
    float mv = hmd[(size_t)v * 16 + 8 + d];
    float coef = -0.5f * grav[0];
    float acc = 0.f;
#pragma unroll
    for (int dir = 0; dir < 2; dir++) {
        const int* start = dir ? start_out : start_in;
        const int* csr   = dir ? csr_out   : csr_in;
        int e1 = start[v + 1];
        int e = start[v];
        for (; e + 3 < e1; e += 4) {
            int u0 = csr[e], u1 = csr[e + 1], u2 = csr[e + 2], u3 = csr[e + 3];
            float h0 = hmd[(size_t)u0 * 16 + d], m0 = hmd[(size_t)u0 * 16 + 8 + d];
            float h1 = hmd[(size_t)u1 * 16 + d], m1 = hmd[(size_t)u1 * 16 + 8 + d];
            float h2 = hmd[(size_t)u2 * 16 + d], m2 = hmd[(size_t)u2 * 16 + 8 + d];
            float h3 = hmd[(size_t)u3 * 16 + d], m3 = hmd[(size_t)u3 * 16 + 8 + d];
            float d0 = hv - h0, d1 = hv - h1, d2 = hv - h2, d3 = hv - h3;
            float e20 = d0 * d0, e21 = d1 * d1, e22 = d2 * d2, e23 = d3 * d3;
            float S0 = mv * m0, S1 = mv * m1, S2 = mv * m2, S3 = mv * m3;
            e20 += __shfl_xor(e20, 1); S0 += __shfl_xor(S0, 1);
            e21 += __shfl_xor(e21, 1); S1 += __shfl_xor(S1, 1);
            e22 += __shfl_xor(e22, 1); S2 += __shfl_xor(S2, 1);
            e23 += __shfl_xor(e23, 1); S3 += __shfl_xor(S3, 1);
            e20 += __shfl_xor(e20, 2); S0 += __shfl_xor(S0, 2);
            e21 += __shfl_xor(e21, 2); S1 += __shfl_xor(S1, 2);
            e22 += __shfl_xor(e22, 2); S2 += __shfl_xor(S2, 2);
            e23 += __shfl_xor(e23, 2); S3 += __shfl_xor(S3, 2);
            e20 += __shfl_xor(e20, 4); S0 += __shfl_xor(S0, 4);
            e21 += __shfl_xor(e21, 4); S1 += __shfl_xor(S1, 4);
            e22 += __shfl_xor(e22, 4); S2 += __shfl_xor(S2, 4);
            e23 += __shfl_xor(e23, 4); S3 += __shfl_xor(S3, 4);
            float c0 = coef * S0 / (e20 * sqrtf(e20));
            float c1 = coef * S1 / (e21 * sqrtf(e21));
            float c2 = coef * S2 / (e22 * sqrtf(e22));
            float c3 = coef * S3 / (e23 * sqrtf(e23));
            acc = fmaf(c0, d0, acc); acc = fmaf(c1, d1, acc);
            acc = fmaf(c2, d2, acc); acc = fmaf(c3, d3, acc);
        }
        for (; e < e1; e++) {
            int u = csr[e];
            float hu = hmd[(size_t)u * 16 + d];
            float mu = hmd[(size_t)u * 16 + 8 + d];
            float dif = hv - hu;
            float e2 = dif * dif;
            float S  = mv * mu;
            e2 += __shfl_xor(e2, 1); S += __shfl_xor(S, 1);
            e2 += __shfl_xor(e2, 2); S += __shfl_xor(S, 2);
            e2 += __shfl_xor(e2, 4); S += __shfl_xor(S, 4);
            float c = coef * S / (e2 * sqrtf(e2));
            acc = fmaf(c, dif, acc);
        }
    }
    gh[(size_t)v * DD + d] = acc;
    bgh[(size_t)v * DD + d] = b[v] * acc;
}

// out[:, :D] = gh + a * AggOut(gz1b)   (unroll-4 gather)
__global__ void k_out_agg(const int* __restrict__ start, const int* __restrict__ csr,
                          const float* __restrict__ gz1b, const float* __restrict__ gh,
                          const float* __restrict__ a, float* __restrict__ out, int N) {
    int t = blockIdx.x * blockDim.x + threadIdx.x;
    int v = t >> 3, d = t & 7;
    if (v >= N) return;
    int e0 = start[v], e1 = start[v + 1];
    float s = 0.f;
    int e = e0;
    for (; e + 3 < e1; e += 4) {
        int u0 = csr[e], u1 = csr[e + 1], u2 = csr[e + 2], u3 = csr[e + 3];
        float x0 = gz1b[(size_t)u0 * DD + d], x1 = gz1b[(size_t)u1 * DD + d];
        float x2 = gz1b[(size_t)u2 * DD + d], x3 = gz1b[(size_t)u3 * DD + d];
        s += (x0 + x1) + (x2 + x3);
    }
    for (; e < e1; e++) s += gz1b[(size_t)csr[e] * DD + d];
    out[(size_t)v * 2 * DD + d] = fmaf(a[v], s, gh[(size_t)v * DD + d]);
}

// ================= fused gather + dense MLP node kernels ====================
// Phase 1: 8 lanes/node gather neighbor features into LDS (unroll-4).
// Phase 2: 1 thread/node MLP over H=256 hidden units, weights in LDS.

__launch_bounds__(256)
__global__ void k_fwd_fused(const int* __restrict__ start, const int* __restrict__ csr,
                            const float* __restrict__ qn, const float* __restrict__ a,
                            const float* __restrict__ b,
                            const float* __restrict__ W1, const float* __restrict__ b1,
                            const float* __restrict__ W2,
                            float* __restrict__ z1out, float* __restrict__ ya, int N) {
    __shared__ float sW1t[HH * DD];   // [j][d] = W1[d][j]
    __shared__ float sW2[HH * DD];    // [j][d]
    __shared__ float sb1[HH];
    __shared__ float sAgg[256 * DD];
    for (int i = threadIdx.x; i < HH * DD; i += blockDim.x) {
        sW1t[(i & 255) * 8 + (i >> 8)] = W1[i];   // coalesced global read
        sW2[i] = W2[i];
    }
    for (int i = threadIdx.x; i < HH; i += blockDim.x) sb1[i] = b1[i];

    int base = blockIdx.x * 256;
    int d = threadIdx.x & 7;
#pragma unroll
    for (int g = 0; g < 8; g++) {
        int local = g * 32 + (threadIdx.x >> 3);
        int v = base + local;
        float s = 0.f;
        if (v < N) {
            int e0 = start[v], e1 = start[v + 1];
            int e = e0;
            for (; e + 3 < e1; e += 4) {
                int u0 = csr[e], u1 = csr[e + 1], u2 = csr[e + 2], u3 = csr[e + 3];
                float x0 = qn[(size_t)u0 * DD + d], x1 = qn[(size_t)u1 * DD + d];
                float x2 = qn[(size_t)u2 * DD + d], x3 = qn[(size_t)u3 * DD + d];
                s += (x0 + x1) + (x2 + x3);
            }
            for (; e < e1; e++) s += qn[(size_t)csr[e] * DD + d];
        }
        sAgg[local * DD + d] = s;
    }
    __syncthreads();

    int v = base + threadIdx.x;
    if (v >= N) return;
    float z[DD], y[DD];
    float bv = b[v];
#pragma unroll
    for (int dd = 0; dd < DD; dd++) { z[dd] = bv * sAgg[threadIdx.x * DD + dd]; y[dd] = 0.f; }
#pragma unroll
    for (int dd = 0; dd < DD; dd++) z1out[(size_t)v * DD + dd] = z[dd];
    for (int j = 0; j < HH; j++) {
        const float4* w1r = (const float4*)(sW1t + j * DD);
        const float4* w2r = (const float4*)(sW2 + j * DD);
        float4 wa = w1r[0], wb = w1r[1];
        float u = sb1[j];
        u = fmaf(z[0], wa.x, u); u = fmaf(z[1], wa.y, u);
        u = fmaf(z[2], wa.z, u); u = fmaf(z[3], wa.w, u);
        u = fmaf(z[4], wb.x, u); u = fmaf(z[5], wb.y, u);
        u = fmaf(z[6], wb.z, u); u = fmaf(z[7], wb.w, u);
        float hh = fmaxf(u, 0.f);
        float4 va = w2r[0], vb = w2r[1];
        y[0] = fmaf(hh, va.x, y[0]); y[1] = fmaf(hh, va.y, y[1]);
        y[2] = fmaf(hh, va.z, y[2]); y[3] = fmaf(hh, va.w, y[3]);
        y[4] = fmaf(hh, vb.x, y[4]); y[5] = fmaf(hh, vb.y, y[5]);
        y[6] = fmaf(hh, vb.z, y[6]); y[7] = fmaf(hh, vb.w, y[7]);
    }
    float av = a[v];
#pragma unroll
    for (int dd = 0; dd < DD; dd++) ya[(size_t)v * DD + dd] = av * y[dd];
}

__launch_bounds__(256)
__global__ void k_bwd_fused(const int* __restrict__ start, const int* __restrict__ csr,
                            const float* __restrict__ bgh, const float* __restrict__ z1,
                            const float* __restrict__ a, const float* __restrict__ b,
                            const float* __restrict__ W1, const float* __restrict__ b1,
                            const float* __restrict__ W2,
                            float* __restrict__ gz1b, int N) {
    __shared__ float sW1t[HH * DD];
    __shared__ float sW2[HH * DD];
    __shared__ float sb1[HH];
    __shared__ float sAgg[256 * DD];
    for (int i = threadIdx.x; i < HH * DD; i += blockDim.x) {
        sW1t[(i & 255) * 8 + (i >> 8)] = W1[i];
        sW2[i] = W2[i];
    }
    for (int i = threadIdx.x; i < HH; i += blockDim.x) sb1[i] = b1[i];

    int base = blockIdx.x * 256;
    int d = threadIdx.x & 7;
#pragma unroll
    for (int g = 0; g < 8; g++) {
        int local = g * 32 + (threadIdx.x >> 3);
        int v = base + local;
        float s = 0.f;
        if (v < N) {
            int e0 = start[v], e1 = start[v + 1];
            int e = e0;
            for (; e + 3 < e1; e += 4) {
                int u0 = csr[e], u1 = csr[e + 1], u2 = csr[e + 2], u3 = csr[e + 3];
                float x0 = bgh[(size_t)u0 * DD + d], x1 = bgh[(size_t)u1 * DD + d];
                float x2 = bgh[(size_t)u2 * DD + d], x3 = bgh[(size_t)u3 * DD + d];
                s += (x0 + x1) + (x2 + x3);
            }
            for (; e < e1; e++) s += bgh[(size_t)csr[e] * DD + d];
        }
        sAgg[local * DD + d] = s;
    }
    __syncthreads();

    int v = base + threadIdx.x;
    if (v >= N) return;
    float z[DD], gq[DD], gz[DD];
    const float4* z1p = (const float4*)(z1 + (size_t)v * DD);
    float4 za = z1p[0], zb = z1p[1];
    z[0] = za.x; z[1] = za.y; z[2] = za.z; z[3] = za.w;
    z[4] = zb.x; z[5] = zb.y; z[6] = zb.z; z[7] = zb.w;
#pragma unroll
    for (int dd = 0; dd < DD; dd++) {
        gq[dd] = sAgg[threadIdx.x * DD + dd];
        gz[dd] = 0.f;
    }
    float av = a[v];
    for (int j = 0; j < HH; j++) {
        const float4* w1r = (const float4*)(sW1t + j * DD);
        const float4* w2r = (const float4*)(sW2 + j * DD);
        float4 wa = w1r[0], wb = w1r[1];
        float u = sb1[j];
        u = fmaf(z[0], wa.x, u); u = fmaf(z[1], wa.y, u);
        u = fmaf(z[2], wa.z, u); u = fmaf(z[3], wa.w, u);
        u = fmaf(z[4], wb.x, u); u = fmaf(z[5], wb.y, u);
        u = fmaf(z[6], wb.z, u); u = fmaf(z[7], wb.w, u);
        float4 va = w2r[0], vb = w2r[1];
        float g = gq[0] * va.x + gq[1] * va.y + gq[2] * va.z + gq[3] * va.w
                + gq[4] * vb.x + gq[5] * vb.y + gq[6] * vb.z + gq[7] * vb.w;
        g = (u > 0.f) ? av * g : 0.f;
        gz[0] = fmaf(g, wa.x, gz[0]); gz[1] = fmaf(g, wa.y, gz[1]);
        gz[2] = fmaf(g, wa.z, gz[2]); gz[3] = fmaf(g, wa.w, gz[3]);
        gz[4] = fmaf(g, wb.x, gz[4]); gz[5] = fmaf(g, wb.y, gz[5]);
        gz[6] = fmaf(g, wb.z, gz[6]); gz[7] = fmaf(g, wb.w, gz[7]);
    }
    float bv = b[v];
#pragma unroll
    for (int dd = 0; dd < DD; dd++) gz1b[(size_t)v * DD + dd] = bv * gz[dd];
}

// ============================== launch =====================================

extern "C" void kernel_launch(void* const* d_in, const int* in_sizes, int n_in,
                              void* d_out, int out_size, void* d_ws, size_t ws_size,
                              hipStream_t stream) {
    const float* q    = (const float*)d_in[0];
    const float* p    = (const float*)d_in[1];
    const float* M    = (const float*)d_in[2];
    const int*   src  = (const int*)d_in[3];
    const int*   dst  = (const int*)d_in[4];
    const float* W1   = (const float*)d_in[5];
    const float* b1   = (const float*)d_in[6];
    const float* W2   = (const float*)d_in[7];
    const float* b2   = (const float*)d_in[8];
    const float* grav = (const float*)d_in[9];
    float* out = (float*)d_out;

    int N = in_sizes[0] / DD;
    int E = in_sizes[3];
    size_t n = (size_t)N;
    int NB = (N + 511) >> 9;   // coarse buckets (<=256 for N<=131072)

    // ---- float region (58N floats) ----
    float* ws   = (float*)d_ws;
    float* a_   = ws;             // N
    float* b_   = ws + n;         // N
    float* qn   = ws + 2  * n;    // 8N
    float* z1   = ws + 10 * n;    // 8N
    float* ya   = ws + 18 * n;    // 8N  (reused as gz1b)
    float* hmd  = ws + 26 * n;    // 16N (h slots 0..7, md slots 8..15)
    float* gh   = ws + 42 * n;    // 8N
    float* bgh  = ws + 50 * n;    // 8N
    float* gz1b = ya;

    // ---- int region ----
    int* iw        = (int*)(ws + 58 * n);
    int* csr_in    = iw;                       // E
    int* csr_out   = iw + (size_t)E;           // E
    int* start_in  = iw + 2 * (size_t)E;       // N+1
    int* start_out = start_in + n + 1;         // N+1
    int* gHistIn   = start_out + n + 1;        // 256
    int* gHistOut  = gHistIn + 256;            // 256
    int* cStartIn  = gHistOut + 256;           // NB+1
    int* cStartOut = cStartIn + NB + 1;        // NB+1
    int* cCurIn    = cStartOut + NB + 1;       // NB
    int* cCurOut   = cCurIn + NB;              // NB
    int* iwEnd     = cCurOut + NB;
    // partition scratch (E ints): alias gh/bgh float region (dead during CSR build)
    int* P = (E <= 16 * (long long)n) ? (int*)(ws + 42 * n) : iwEnd;

    hipMemsetAsync(gHistIn, 0, 512 * sizeof(int), stream);

    const int tb = 256;
    int gbN = (N + tb - 1) / tb;
    int gb8 = (int)((8 * n + tb - 1) / tb);
    int gbC = (E + CH - 1) / CH;

    // CSR build (bucketed counting sort, both directions; P reused)
    k_coarse   <<<gbC, tb, 0, stream>>>(src, dst, gHistIn, gHistOut, NB, E);
    k_cscan    <<<1, 256, 0, stream>>>(gHistIn, gHistOut, cStartIn, cStartOut,
                                       cCurIn, cCurOut, NB, E);
    k_partition<<<gbC, tb, 0, stream>>>(dst, src, cCurIn, P, NB, E);
    k_fine     <<<NB, 512, 0, stream>>>(cStartIn, P, start_in, csr_in, N);
    k_partition<<<gbC, tb, 0, stream>>>(src, dst, cCurOut, P, NB, E);
    k_fine     <<<NB, 512, 0, stream>>>(cStartOut, P, start_out, csr_out, N);
    k_prep     <<<gbN, tb, 0, stream>>>(q, p, M, start_in, start_out,
                                        a_, b_, hmd, qn, out, N, E);

    // forward: z1 = b ⊙ AggIn(a ⊙ q); ya = a ⊙ (relu(z1@W1+b1)@W2)   [fused]
    k_fwd_fused<<<gbN, tb, 0, stream>>>(start_in, csr_in, qn, a_, b_,
                                        W1, b1, W2, z1, ya, N);
    // h = b ⊙ AggIn(ya) + b2 + q  (into hmd slots 0..7)
    k_h_agg    <<<gb8, tb, 0, stream>>>(start_in, csr_in, ya, b_, q, b2, hmd, N);
    // gravity gradient (symmetric per-node, interleaved hmd, unroll-4)
    k_gh       <<<gb8, tb, 0, stream>>>(start_in, csr_in, start_out, csr_out,
                                        hmd, b_, grav, gh, bgh, N);
    // gq2 = AggOut(bgh); gz1b = b ⊙ ((a⊙(gq2@W2^T) ⊙ relu') @ W1^T)   [fused]
    k_bwd_fused<<<gbN, tb, 0, stream>>>(start_out, csr_out, bgh, z1, a_, b_,
                                        W1, b1, W2, gz1b, N);
    // dHdQ = gh + a ⊙ AggOut(gz1b)
    k_out_agg  <<<gb8, tb, 0, stream>>>(start_out, csr_out, gz1b, gh, a_, out, N);
}